// Round 10
// baseline (76.243 us; speedup 1.0000x reference)
//
#include <hip/hip_runtime.h>
#include <math.h>

// Problem dims (fixed by reference)
#define BDIM 2048
#define ODIM 256
#define IDIM 256
#define NZ   8                      // j-splits
#define JBLK (IDIM / NZ)            // 32 j per block
#define NJQ  (JBLK / 4)             // 8 j-quads
#define ZBASE ((float)(IDIM / NZ))  // 32.0f exactly; per-z share of the +IDIM base

typedef float v2f __attribute__((ext_vector_type(2)));

// out[b,o] = IDIM + C * sum_j 1/(D - 2at*cos(phi0 + x[b,j] + p[o,j]))
//   C = (t^2-1)(1-a^2),  D = 1+(at)^2
// cos(x'+p) = cos x' cos p - sin x' sin p =>
//   den = D + mc*pc + ms*ps,  mc=-2at*cos(phi0+x), ms=2at*sin(phi0+x)
//
// R10: asymmetric register tile. Block tile 64b x 128o, 256 threads,
// thread tile 4b x 8o (4 o-pairs). Per jq all 16 P-b128 are held in
// registers across the k-loop -> LDS bytes/cell-j = 3 (vs 4 at 4x4).
//   As4[b][2jq] = {mc(j0..3)}, As4[b][2jq+1] = {ms(j0..3)}
//   SP4[j][pair][tx] = {pc(o_lo), pc(o_hi), ps(o_lo), ps(o_hi)},
//        o = o0 + pair*32 + hi*16 + tx,  pair = 0..3
// f32 everywhere in the hot loop (zero cvt), quad-rcp tail, atomic
// epilogue with ZBASE folded per z-plane.

__global__ __launch_bounds__(256, 2)
void photonic_fused(const float* __restrict__ X,   // [BDIM][IDIM]
                    const float* __restrict__ P,   // [ODIM][IDIM]
                    float* __restrict__ Out,       // [BDIM][ODIM] (+= semantics)
                    float phi0, float m2at, float p2at,
                    float Dc, float Cnum) {
    __shared__ float4 As4[64][17];       // 17408 B (slot 16 = pad)
    __shared__ float4 SP4[JBLK][4][16];  // 32768 B

    const int tid = threadIdx.x;
    const int tx  = tid & 15;            // o sub-index (16 cols)
    const int ty  = tid >> 4;            // b sub-index (16 rows)
    const int o0  = blockIdx.x * 128;    // 2 o-tiles
    const int b0  = blockIdx.y * 64;     // 32 b-tiles
    const int j0  = blockIdx.z * JBLK;   // 8 j-splits

    // ---- fused prologue ----
    // A-side: 64 b-rows x 32 j  (thread covers one 4-j chunk, 2 iters)
    #pragma unroll
    for (int i = 0; i < 2; ++i) {
        const int r  = (tid >> 3) + 32 * i;   // 0..63
        const int jq = tid & 7;               // 0..7
        float s0, c0, s1, c1, s2, c2, s3, c3;
        float4 x = *(const float4*)(X + (size_t)(b0 + r) * IDIM + j0 + 4 * jq);
        __sincosf(phi0 + x.x, &s0, &c0);
        __sincosf(phi0 + x.y, &s1, &c1);
        __sincosf(phi0 + x.z, &s2, &c2);
        __sincosf(phi0 + x.w, &s3, &c3);
        As4[r][2 * jq]     = make_float4(m2at * c0, m2at * c1, m2at * c2, m2at * c3);
        As4[r][2 * jq + 1] = make_float4(p2at * s0, p2at * s1, p2at * s2, p2at * s3);
    }
    // P-side: 128 o-rows x 32 j (thread covers one 4-j chunk, 4 iters)
    #pragma unroll
    for (int i = 0; i < 4; ++i) {
        const int r  = (tid >> 3) + 32 * i;   // o_l = 0..127
        const int jq = tid & 7;
        float s0, c0, s1, c1, s2, c2, s3, c3;
        float4 pv = *(const float4*)(P + (size_t)(o0 + r) * IDIM + j0 + 4 * jq);
        __sincosf(pv.x, &s0, &c0);
        __sincosf(pv.y, &s1, &c1);
        __sincosf(pv.z, &s2, &c2);
        __sincosf(pv.w, &s3, &c3);
        const int pr  = r >> 5;               // 0..3
        const int hi  = (r >> 4) & 1;         // 0/1
        const int tx_ = r & 15;
        float cs[4] = {c0, c1, c2, c3};
        float ss[4] = {s0, s1, s2, s3};
        #pragma unroll
        for (int jj = 0; jj < 4; ++jj) {
            float* cell = (float*)&SP4[4 * jq + jj][pr][tx_];
            cell[hi]     = cs[jj];
            cell[2 + hi] = ss[jj];
        }
    }
    __syncthreads();

    v2f acc[4][4];
    #pragma unroll
    for (int k = 0; k < 4; ++k)
        #pragma unroll
        for (int p = 0; p < 4; ++p) acc[k][p] = (v2f){0.f, 0.f};

    const v2f D2 = {Dc, Dc};

    for (int jq = 0; jq < NJQ; ++jq) {
        // P operands for this j-quad: 16 b128, live across the whole k-loop
        float4 q[4][4];                      // [j][pair]
        #pragma unroll
        for (int j = 0; j < 4; ++j)
            #pragma unroll
            for (int p = 0; p < 4; ++p)
                q[j][p] = SP4[4 * jq + j][p][tx];

        #pragma unroll
        for (int k = 0; k < 4; ++k) {
            float4 mc4 = As4[ty + 16 * k][2 * jq];
            float4 ms4 = As4[ty + 16 * k][2 * jq + 1];
            float mcf[4] = {mc4.x, mc4.y, mc4.z, mc4.w};
            float msf[4] = {ms4.x, ms4.y, ms4.z, ms4.w};
            #pragma unroll
            for (int p = 0; p < 4; ++p) {
                v2f d[4];
                #pragma unroll
                for (int j = 0; j < 4; ++j) {
                    v2f pc = {q[j][p].x, q[j][p].y};
                    v2f ps = {q[j][p].z, q[j][p].w};
                    v2f t = __builtin_elementwise_fma((v2f){msf[j], msf[j]}, ps, D2);
                    d[j]  = __builtin_elementwise_fma((v2f){mcf[j], mcf[j]}, pc, t);
                }
                // quad-rcp over the 4 j's, vectorized over the o-pair
                v2f p01 = d[0] * d[1], p23 = d[2] * d[3];
                v2f s01 = d[0] + d[1], s23 = d[2] + d[3];
                v2f n = __builtin_elementwise_fma(s01, p23, s23 * p01);
                v2f qq = p01 * p23;
                v2f r = {__builtin_amdgcn_rcpf(qq.x), __builtin_amdgcn_rcpf(qq.y)};
                acc[k][p] = __builtin_elementwise_fma(n, r, acc[k][p]);
            }
        }
    }

    // ---- atomic epilogue: base folded in as +ZBASE per z-plane ----
    #pragma unroll
    for (int k = 0; k < 4; ++k)
        #pragma unroll
        for (int p = 0; p < 4; ++p) {
            int b = b0 + ty + 16 * k;
            int o = o0 + p * 32 + tx;
            unsafeAtomicAdd(&Out[(size_t)b * ODIM + o],      fmaf(Cnum, acc[k][p].x, ZBASE));
            unsafeAtomicAdd(&Out[(size_t)b * ODIM + o + 16], fmaf(Cnum, acc[k][p].y, ZBASE));
        }
}

extern "C" void kernel_launch(void* const* d_in, const int* in_sizes, int n_in,
                              void* d_out, int out_size, void* d_ws, size_t ws_size,
                              hipStream_t stream) {
    const float* X = (const float*)d_in[0];   // input_matrix [2048,256] f32
    const float* P = (const float*)d_in[1];   // phase_offset [256,256] f32
    float* Out = (float*)d_out;               // [2048,256] f32

    const double RADIUS = 5e-6, KAPPA = 0.1, N_EFF = 3.48, LAMBDA = 1.55e-6, LOSS_A = 0.99;
    const double TWO_PI = 6.283185307179586476925286766559;
    const double t  = sqrt(1.0 - KAPPA);
    const double a  = LOSS_A;
    const double at = a * t;
    const double phi0 = fmod(TWO_PI * N_EFF * (TWO_PI * RADIUS) / LAMBDA, TWO_PI);
    const double D    = 1.0 + at * at;
    const double Cnum = (t * t - 1.0) * (1.0 - a * a);   // num - den (constant)

    // 2 o-tiles x 32 b-tiles x 8 j-splits = 512 blocks of 256 thr (2/CU)
    dim3 grid(ODIM / 128, BDIM / 64, NZ);
    photonic_fused<<<grid, 256, 0, stream>>>(
        X, P, Out,
        (float)phi0, (float)(-2.0 * at), (float)(2.0 * at),
        (float)D, (float)Cnum);
}